// Round 7
// baseline (657.665 us; speedup 1.0000x reference)
//
#include <hip/hip_runtime.h>

// Problem constants (fixed by reference)
#define N_NODES 2048
#define EMBED   32
#define B_BATCH 16
#define INP     32
#define OUTC    32
#define NCOL    512
#define CHEB_K  3
#define NB      512   // persistent grid: 2 blocks/CU on 256 CUs (co-resident)

// R6: ONE persistent kernel with a device-scope grid barrier. R5/R6 evidence:
// 9 serial dispatches cost ~130us of gaps/re-warm while real work is ~40us;
// two structurally different k_finals both "measured" 51us. Fuse everything.

__device__ __forceinline__ void grid_sync(unsigned* bar) {
    __syncthreads();
    if (threadIdx.x == 0) {
        __threadfence();   // agent-scope release (L2 writeback on gfx950)
        unsigned g = __hip_atomic_load(&bar[1], __ATOMIC_RELAXED, __HIP_MEMORY_SCOPE_AGENT);
        unsigned a = __hip_atomic_fetch_add(&bar[0], 1u, __ATOMIC_ACQ_REL, __HIP_MEMORY_SCOPE_AGENT);
        if (a == NB - 1) {
            __hip_atomic_store(&bar[0], 0u, __ATOMIC_RELAXED, __HIP_MEMORY_SCOPE_AGENT);
            __hip_atomic_fetch_add(&bar[1], 1u, __ATOMIC_RELEASE, __HIP_MEMORY_SCOPE_AGENT);
        } else {
            while (__hip_atomic_load(&bar[1], __ATOMIC_ACQUIRE, __HIP_MEMORY_SCOPE_AGENT) == g)
                __builtin_amdgcn_s_sleep(2);
        }
        __threadfence();   // agent-scope acquire (cache invalidate)
    }
    __syncthreads();
}

__global__ __launch_bounds__(256, 2) void k_fused(
    const float* __restrict__ XT, const float* __restrict__ adj,
    const float* __restrict__ gammap, const float* __restrict__ W,
    const float* __restrict__ bp, const float* __restrict__ p,
    const float* __restrict__ pb, const float* __restrict__ drop,
    float* __restrict__ Ehat, float* __restrict__ Vp,   // Vp aliased as Mp
    float* __restrict__ Psum, float* __restrict__ inv,
    float* __restrict__ U, float* __restrict__ V1, float* __restrict__ V1p,
    float* __restrict__ V2, float* __restrict__ qpart,
    unsigned* __restrict__ bar, float* __restrict__ out)
{
    __shared__ float sm[5760];        // 23040 B, phase-aliased
    const int tid = threadIdx.x;
    const int bid = blockIdx.x;

    // ---------------- Phase 1: gram tiles (1024 tiles over NB blocks) -------
    {
        float* ai  = sm;              // [64][36]
        float* ajT = sm + 2304;       // [32][68]
        float* nI  = sm + 4480;       // [64]
        float* nJ  = sm + 4544;       // [64]
        float* rm  = sm + 4608;       // [64][17]
        const float gamma = gammap[0];
        for (int tile = bid; tile < 1024; tile += NB) {
            const int j0 = (tile & 31) * 64;
            const int i0 = (tile >> 5) * 64;
            __syncthreads();          // protect LDS across tile iterations
#pragma unroll
            for (int r = 0; r < 8; r++) {
                const int idx = r * 256 + tid;       // 0..2047
                ai[(idx >> 5) * 36 + (idx & 31)]  = adj[(size_t)(i0 + (idx >> 5)) * EMBED + (idx & 31)];
                ajT[(idx & 31) * 68 + (idx >> 5)] = adj[(size_t)(j0 + (idx >> 5)) * EMBED + (idx & 31)];
            }
            __syncthreads();
            if (tid < 64) {
                float s = 0.f;
#pragma unroll
                for (int k = 0; k < 32; k++) { const float v = ai[tid * 36 + k]; s += v * v; }
                nI[tid] = s;
            } else if (tid < 128) {
                const int col = tid - 64;
                float s = 0.f;
#pragma unroll
                for (int k = 0; k < 32; k++) { const float v = ajT[k * 68 + col]; s += v * v; }
                nJ[col] = s;
            }
            __syncthreads();
            const int ti = tid >> 4, tj = tid & 15;
            float acc[4][4] = {};
#pragma unroll
            for (int k4 = 0; k4 < 8; k4++) {
                float4 a4[4], b4[4];
#pragma unroll
                for (int r = 0; r < 4; r++) a4[r] = *(const float4*)&ai[(ti * 4 + r) * 36 + k4 * 4];
#pragma unroll
                for (int kk = 0; kk < 4; kk++) b4[kk] = *(const float4*)&ajT[(k4 * 4 + kk) * 68 + tj * 4];
#pragma unroll
                for (int r = 0; r < 4; r++) {
                    acc[r][0] += a4[r].x * b4[0].x + a4[r].y * b4[1].x + a4[r].z * b4[2].x + a4[r].w * b4[3].x;
                    acc[r][1] += a4[r].x * b4[0].y + a4[r].y * b4[1].y + a4[r].z * b4[2].y + a4[r].w * b4[3].y;
                    acc[r][2] += a4[r].x * b4[0].z + a4[r].y * b4[1].z + a4[r].z * b4[2].z + a4[r].w * b4[3].z;
                    acc[r][3] += a4[r].x * b4[0].w + a4[r].y * b4[1].w + a4[r].z * b4[2].w + a4[r].w * b4[3].w;
                }
            }
#pragma unroll
            for (int r = 0; r < 4; r++) {
                const int i = i0 + ti * 4 + r;
                const float ni = nI[ti * 4 + r];
                float e[4];
#pragma unroll
                for (int c = 0; c < 4; c++) {
                    const float dist = ni + nJ[tj * 4 + c] - 2.f * acc[r][c];
                    e[c] = __expf(__expf(-gamma * dist));
                }
                rm[(ti * 4 + r) * 17 + tj] = e[0] + e[1] + e[2] + e[3];
                const float4 dr = *(const float4*)&drop[(size_t)i * N_NODES + j0 + tj * 4];
                *(float4*)(&Ehat[(size_t)i * N_NODES + j0 + tj * 4]) =
                    make_float4(e[0] * dr.x, e[1] * dr.y, e[2] * dr.z, e[3] * dr.w);
            }
            __syncthreads();
            if (tid < 64) {
                float s = 0.f;
#pragma unroll
                for (int t = 0; t < 16; t++) s += rm[tid * 17 + t];
                Psum[(size_t)(tile & 31) * N_NODES + i0 + tid] = s;
            }
        }
    }
    grid_sync(bar);

    // ---------------- Phase 2: V1 partials (inv computed per block) ---------
    {
        float* invL = sm;            // 64
        float* red  = sm + 64;       // 256
        float* Us   = sm + 320;      // 2048
        const int nt = bid >> 5;     // 0..15
        const int mc = bid & 31;     // 0..31
        const int m0 = mc * 64;
        if (bid < 512) {
            const int r = tid & 63, g = tid >> 6;
            float s = 0.f;
#pragma unroll
            for (int t = 0; t < 8; t++) s += Psum[(size_t)(g * 8 + t) * N_NODES + m0 + r];
            red[tid] = s;
            __syncthreads();
            if (tid < 64)
                invL[tid] = 1.0f / (red[tid] + red[64 + tid] + red[128 + tid] + red[192 + tid]);
            __syncthreads();
#pragma unroll
            for (int rr = 0; rr < 8; rr++) {
                const int idx = rr * 256 + tid;      // 0..2047
                const int row = idx >> 5;
                const float u = p[m0 + row] * adj[(size_t)m0 * EMBED + idx];
                Us[idx] = invL[row] * u;
                if (nt == 0) U[(size_t)m0 * EMBED + idx] = u;
            }
            if (nt == 0 && tid < 64) inv[m0 + tid] = invL[tid];
            __syncthreads();
            if (nt == 0) {
                const int d = tid & 31, g2 = tid >> 5;
                float qs = 0.f;
#pragma unroll
                for (int r2 = 0; r2 < 8; r2++) {
                    const int row = g2 * 8 + r2;
                    qs += p[m0 + row] * adj[(size_t)(m0 + row) * EMBED + d];
                }
                red[tid] = qs;
                __syncthreads();
                if (g2 == 0) {
                    float t = 0.f;
#pragma unroll
                    for (int gg = 0; gg < 8; gg++) t += red[gg * 32 + d];
                    qpart[mc * EMBED + d] = t;
                }
            }
            // A^T pass
            const int n  = nt * 128 + (tid & 127);
            const int dh = (tid >> 7) * 16;
            float4 a0 = {}, a1 = {}, a2 = {}, a3 = {};
            for (int mm = 0; mm < 64; mm++) {
                const float a = Ehat[(size_t)(m0 + mm) * N_NODES + n];
                const float4* u4 = (const float4*)(&Us[mm * 32 + dh]);
                const float4 u0 = u4[0], u1 = u4[1], u2 = u4[2], u3 = u4[3];
                a0.x += a * u0.x; a0.y += a * u0.y; a0.z += a * u0.z; a0.w += a * u0.w;
                a1.x += a * u1.x; a1.y += a * u1.y; a1.z += a * u1.z; a1.w += a * u1.w;
                a2.x += a * u2.x; a2.y += a * u2.y; a2.z += a * u2.z; a2.w += a * u2.w;
                a3.x += a * u3.x; a3.y += a * u3.y; a3.z += a * u3.z; a3.w += a * u3.w;
            }
            float4* o4 = (float4*)(Vp + (size_t)mc * (N_NODES * EMBED) + (size_t)n * EMBED + dh);
            o4[0] = a0; o4[1] = a1; o4[2] = a2; o4[3] = a3;
        }
    }
    grid_sync(bar);

    // ---------------- Phase 3: reduce Vp -> V1, V1p -------------------------
    if (bid < 256) {
        const int idx = bid * 256 + tid;             // 0..65535
        float s = 0.f;
#pragma unroll
        for (int c = 0; c < 32; c++) s += Vp[(size_t)c * (N_NODES * EMBED) + idx];
        V1[idx] = s;
        V1p[idx] = inv[idx >> 5] * s;
    }
    grid_sync(bar);

    // ---------------- Phase 4: V2 partials ----------------------------------
    if (bid < 512) {
        float* Us = sm;              // 2048
        const int nt = bid >> 5;
        const int mc = bid & 31;
        const int m0 = mc * 64;
#pragma unroll
        for (int rr = 0; rr < 8; rr++) {
            const int idx = rr * 256 + tid;
            Us[idx] = V1p[(size_t)m0 * EMBED + idx];
        }
        __syncthreads();
        const int n  = nt * 128 + (tid & 127);
        const int dh = (tid >> 7) * 16;
        float4 a0 = {}, a1 = {}, a2 = {}, a3 = {};
        for (int mm = 0; mm < 64; mm++) {
            const float a = Ehat[(size_t)(m0 + mm) * N_NODES + n];
            const float4* u4 = (const float4*)(&Us[mm * 32 + dh]);
            const float4 u0 = u4[0], u1 = u4[1], u2 = u4[2], u3 = u4[3];
            a0.x += a * u0.x; a0.y += a * u0.y; a0.z += a * u0.z; a0.w += a * u0.w;
            a1.x += a * u1.x; a1.y += a * u1.y; a1.z += a * u1.z; a1.w += a * u1.w;
            a2.x += a * u2.x; a2.y += a * u2.y; a2.z += a * u2.z; a2.w += a * u2.w;
            a3.x += a * u3.x; a3.y += a * u3.y; a3.z += a * u3.z; a3.w += a * u3.w;
        }
        float4* o4 = (float4*)(Vp + (size_t)mc * (N_NODES * EMBED) + (size_t)n * EMBED + dh);
        o4[0] = a0; o4[1] = a1; o4[2] = a2; o4[3] = a3;
    }
    grid_sync(bar);

    // ---------------- Phase 5: reduce Vp -> V2 ------------------------------
    if (bid < 256) {
        const int idx = bid * 256 + tid;
        float s = 0.f;
#pragma unroll
        for (int c = 0; c < 32; c++) s += Vp[(size_t)c * (N_NODES * EMBED) + idx];
        V2[idx] = s;
    }
    grid_sync(bar);

    // ---------------- Phase 6: M partials (Mp aliases Vp) -------------------
    if (bid < 512) {
        float* xs = sm;              // [32][65] = 2080
        float* vs = sm + 2080;       // [3][1024]
        float* Mp = Vp;
        const int c0 = (bid >> 5) * 32;
        const int n0 = (bid & 31) * 64;
        const int d  = tid >> 3;
        const int cg = (tid & 7) * 4;
#pragma unroll
        for (int r = 0; r < 8; r++) {
            const int idx = r * 256 + tid;           // 0..2047
            xs[(idx >> 6) * 65 + (idx & 63)] = XT[(size_t)(c0 + (idx >> 6)) * N_NODES + n0 + (idx & 63)];
        }
        float acc[3][4] = {};
#pragma unroll
        for (int h = 0; h < 2; h++) {
            __syncthreads();
#pragma unroll
            for (int r = 0; r < 4; r++) {
                const int idx = r * 256 + tid;       // 0..1023
                vs[idx]        = U [(size_t)(n0 + h * 32) * EMBED + idx];
                vs[1024 + idx] = V1[(size_t)(n0 + h * 32) * EMBED + idx];
                vs[2048 + idx] = V2[(size_t)(n0 + h * 32) * EMBED + idx];
            }
            __syncthreads();
#pragma unroll 4
            for (int nn = 0; nn < 32; nn++) {
                const float v0 = vs[nn * 32 + d];
                const float v1 = vs[1024 + nn * 32 + d];
                const float v2 = vs[2048 + nn * 32 + d];
#pragma unroll
                for (int cc = 0; cc < 4; cc++) {
                    const float xv = xs[(cg + cc) * 65 + h * 32 + nn];
                    acc[0][cc] += xv * v0;
                    acc[1][cc] += xv * v1;
                    acc[2][cc] += xv * v2;
                }
            }
        }
#pragma unroll
        for (int k = 0; k < 3; k++) {
            float* dst = Mp + ((size_t)((bid & 31) * 3 + k) * EMBED + d) * NCOL + c0 + cg;
            *(float4*)dst = make_float4(acc[k][0], acc[k][1], acc[k][2], acc[k][3]);
        }
    }
    grid_sync(bar);

    // ---------------- Phase 7: split-d epilogue -----------------------------
    if (bid < 32) {
        const float* Mp = Vp;
        float* wL = sm;              // 3072
        float* mL = sm + 3072;       // 1536
        float* qL = sm + 4608;       // 32
        const int d = bid;
#pragma unroll
        for (int r = 0; r < 12; r++) {
            const int idx = r * 256 + tid;           // 0..3071
            const int k = idx >> 10;
            wL[idx] = W[((size_t)(d * 3 + k) << 10) + (idx & 1023)];
        }
#pragma unroll
        for (int r = 0; r < 6; r++) {
            const int e = r * 256 + tid;             // 0..1535
            const int k = e >> 9;
            const int c = e & 511;
            float s = 0.f;
#pragma unroll
            for (int ch = 0; ch < 32; ch++)
                s += Mp[((size_t)(ch * 3 + k) * EMBED + d) * NCOL + c];
            mL[k * 512 + c] = s;
        }
        if (d == 0 && tid < 32) {
            float s = 0.f;
#pragma unroll
            for (int mc = 0; mc < 32; mc++) s += qpart[mc * EMBED + tid];
            qL[tid] = s;
        }
        __syncthreads();
#pragma unroll
        for (int r = 0; r < 2; r++) {
            const int pair = r * 256 + tid;          // 0..511 = b*32+o
            const int b = pair >> 5;
            const int o = pair & 31;
            float acc = 0.f;
#pragma unroll
            for (int i = 0; i < 32; i++) {
                const float m0 = mL[b * 32 + i];
                const float m1 = mL[512 + b * 32 + i];
                const float m2 = mL[1024 + b * 32 + i];
                const float w0 = wL[i * 32 + o];
                const float w1 = wL[1024 + i * 32 + o];
                const float w2 = wL[2048 + i * 32 + o];
                acc += m0 * (w0 - w2) + m1 * w1 + 2.f * m2 * w2;
            }
            if (d == 0) {
                float bias = pb[0];
#pragma unroll
                for (int dd = 0; dd < 32; dd++) bias += qL[dd] * bp[dd * OUTC + o];
                acc += bias;
            }
            atomicAdd(&out[pair], acc);
        }
    }
}

// ---------------------------------------------------------------------------
extern "C" void kernel_launch(void* const* d_in, const int* in_sizes, int n_in,
                              void* d_out, int out_size, void* d_ws, size_t ws_size,
                              hipStream_t stream)
{
    const float* x     = (const float*)d_in[0];
    const float* adj   = (const float*)d_in[1];
    const float* gamma = (const float*)d_in[2];
    const float* Wp    = (const float*)d_in[3];
    const float* bp    = (const float*)d_in[4];
    const float* pw    = (const float*)d_in[5];
    const float* pb    = (const float*)d_in[6];
    const float* drop  = (const float*)d_in[7];
    float* out = (float*)d_out;

    float* ws = (float*)d_ws;
    unsigned* bar = (unsigned*)ws;                            // 16 floats reserved
    float* Ehat  = ws + 16;                                   // 4,194,304
    float* Vp    = Ehat + (size_t)N_NODES * N_NODES;          // 2,097,152 (Mp alias)
    float* Psum  = Vp   + (size_t)32 * N_NODES * EMBED;       // 65,536
    float* inv   = Psum + (size_t)32 * N_NODES;               // 2048
    float* U     = inv  + N_NODES;                            // 65,536
    float* V1    = U    + (size_t)N_NODES * EMBED;            // 65,536
    float* V1p   = V1   + (size_t)N_NODES * EMBED;            // 65,536
    float* V2    = V1p  + (size_t)N_NODES * EMBED;            // 65,536
    float* qpart = V2   + (size_t)N_NODES * EMBED;            // 1024

    hipMemsetAsync(bar, 0, 64, stream);
    hipMemsetAsync(out, 0, (size_t)B_BATCH * OUTC * sizeof(float), stream);

    k_fused<<<NB, 256, 0, stream>>>(x, adj, gamma, Wp, bp, pw, pb, drop,
                                    Ehat, Vp, Psum, inv, U, V1, V1p, V2,
                                    qpart, bar, out);
}

// Round 8
// 238.777 us; speedup vs baseline: 2.7543x; 2.7543x over previous
//
#include <hip/hip_runtime.h>

// Problem constants (fixed by reference)
#define N_NODES 2048
#define EMBED   32
#define B_BATCH 16
#define INP     32
#define OUTC    32
#define NCOL    512
#define CHEB_K  3
#define NB      512   // persistent grid: 2 blocks/CU on 256 CUs

// R7: persistent kernel, FENCE-FREE barrier protocol.
// R7(prev) showed agent-scope acquire/release fences cost ~90us/barrier
// (per-XCD L2 wb/inv storms). Fix: (a) write-once workspace layout -> no
// stale copies can exist -> no acquire invalidation needed; (b) phase
// outputs stored with system-scope relaxed atomic stores (write-through to
// coherence point) -> no release wbl2 needed; (c) barrier = monotonic
// relaxed agent-scope counter + s_sleep spin + workgroup acquire fence.

__device__ __forceinline__ void st_sys(float* p, float v) {
    __hip_atomic_store(p, v, __ATOMIC_RELAXED, __HIP_MEMORY_SCOPE_SYSTEM);
}
__device__ __forceinline__ void st_sys4(float* p, float4 v) {
    union { float4 f; unsigned long long u[2]; } c; c.f = v;
    __hip_atomic_store((unsigned long long*)p,       c.u[0], __ATOMIC_RELAXED, __HIP_MEMORY_SCOPE_SYSTEM);
    __hip_atomic_store(((unsigned long long*)p) + 1, c.u[1], __ATOMIC_RELAXED, __HIP_MEMORY_SCOPE_SYSTEM);
}

__device__ __forceinline__ void grid_sync(unsigned* bar, unsigned target) {
    __syncthreads();   // all block stores issued + vmcnt(0) drained
    if (threadIdx.x == 0) {
        __hip_atomic_fetch_add(&bar[0], 1u, __ATOMIC_RELAXED, __HIP_MEMORY_SCOPE_AGENT);
        while (__hip_atomic_load(&bar[0], __ATOMIC_RELAXED, __HIP_MEMORY_SCOPE_AGENT) < target)
            __builtin_amdgcn_s_sleep(8);
    }
    __builtin_amdgcn_fence(__ATOMIC_ACQUIRE, "workgroup");  // compiler barrier, no cache maint.
    __syncthreads();
}

__global__ __launch_bounds__(256, 2) void k_fused(
    const float* __restrict__ XT, const float* __restrict__ adj,
    const float* __restrict__ gammap, const float* __restrict__ W,
    const float* __restrict__ bp, const float* __restrict__ p,
    const float* __restrict__ pb, const float* __restrict__ drop,
    float* __restrict__ Ehat, float* __restrict__ Vpa, float* __restrict__ Vpb,
    float* __restrict__ Mp, float* __restrict__ Psum, float* __restrict__ inv,
    float* __restrict__ V1, float* __restrict__ V1p, float* __restrict__ V2,
    float* __restrict__ qpart, unsigned* __restrict__ bar,
    float* __restrict__ out)
{
    __shared__ float sm[5760];        // 23040 B, phase-aliased
    const int tid = threadIdx.x;
    const int bid = blockIdx.x;

    // ---------------- Phase 1: gram tiles (+ block 0 zeroes out) ------------
    {
        if (bid == 0) { st_sys(&out[tid], 0.f); st_sys(&out[256 + tid], 0.f); }
        float* ai  = sm;              // [64][36]
        float* ajT = sm + 2304;       // [32][68]
        float* nI  = sm + 4480;       // [64]
        float* nJ  = sm + 4544;       // [64]
        float* rm  = sm + 4608;       // [64][17]
        const float gamma = gammap[0];
        for (int tile = bid; tile < 1024; tile += NB) {
            const int j0 = (tile & 31) * 64;
            const int i0 = (tile >> 5) * 64;
            __syncthreads();
#pragma unroll
            for (int r = 0; r < 8; r++) {
                const int idx = r * 256 + tid;       // 0..2047
                ai[(idx >> 5) * 36 + (idx & 31)]  = adj[(size_t)(i0 + (idx >> 5)) * EMBED + (idx & 31)];
                ajT[(idx & 31) * 68 + (idx >> 5)] = adj[(size_t)(j0 + (idx >> 5)) * EMBED + (idx & 31)];
            }
            __syncthreads();
            if (tid < 64) {
                float s = 0.f;
#pragma unroll
                for (int k = 0; k < 32; k++) { const float v = ai[tid * 36 + k]; s += v * v; }
                nI[tid] = s;
            } else if (tid < 128) {
                const int col = tid - 64;
                float s = 0.f;
#pragma unroll
                for (int k = 0; k < 32; k++) { const float v = ajT[k * 68 + col]; s += v * v; }
                nJ[col] = s;
            }
            __syncthreads();
            const int ti = tid >> 4, tj = tid & 15;
            float acc[4][4] = {};
#pragma unroll
            for (int k4 = 0; k4 < 8; k4++) {
                float4 a4[4], b4[4];
#pragma unroll
                for (int r = 0; r < 4; r++) a4[r] = *(const float4*)&ai[(ti * 4 + r) * 36 + k4 * 4];
#pragma unroll
                for (int kk = 0; kk < 4; kk++) b4[kk] = *(const float4*)&ajT[(k4 * 4 + kk) * 68 + tj * 4];
#pragma unroll
                for (int r = 0; r < 4; r++) {
                    acc[r][0] += a4[r].x * b4[0].x + a4[r].y * b4[1].x + a4[r].z * b4[2].x + a4[r].w * b4[3].x;
                    acc[r][1] += a4[r].x * b4[0].y + a4[r].y * b4[1].y + a4[r].z * b4[2].y + a4[r].w * b4[3].y;
                    acc[r][2] += a4[r].x * b4[0].z + a4[r].y * b4[1].z + a4[r].z * b4[2].z + a4[r].w * b4[3].z;
                    acc[r][3] += a4[r].x * b4[0].w + a4[r].y * b4[1].w + a4[r].z * b4[2].w + a4[r].w * b4[3].w;
                }
            }
#pragma unroll
            for (int r = 0; r < 4; r++) {
                const int i = i0 + ti * 4 + r;
                const float ni = nI[ti * 4 + r];
                float e[4];
#pragma unroll
                for (int c = 0; c < 4; c++) {
                    const float dist = ni + nJ[tj * 4 + c] - 2.f * acc[r][c];
                    e[c] = __expf(__expf(-gamma * dist));
                }
                rm[(ti * 4 + r) * 17 + tj] = e[0] + e[1] + e[2] + e[3];
                const float4 dr = *(const float4*)&drop[(size_t)i * N_NODES + j0 + tj * 4];
                st_sys4(&Ehat[(size_t)i * N_NODES + j0 + tj * 4],
                        make_float4(e[0] * dr.x, e[1] * dr.y, e[2] * dr.z, e[3] * dr.w));
            }
            __syncthreads();
            if (tid < 64) {
                float s = 0.f;
#pragma unroll
                for (int t = 0; t < 16; t++) s += rm[tid * 17 + t];
                st_sys(&Psum[(size_t)(tile & 31) * N_NODES + i0 + tid], s);
            }
        }
    }
    grid_sync(bar, NB * 1);

    // ---------------- Phase 2: inv + qpart + V1 partials --------------------
    if (bid < 256) {
        float* invL = sm;            // 128
        float* red  = sm + 128;      // 256
        float* Us   = sm + 384;      // 4096  (128 rows x 32 d)
        const int nt = bid >> 4;     // 0..15 n-tile (128 cols)
        const int mc = bid & 15;     // 0..15 m-chunk (128 rows)
        const int m0 = mc * 128;
        {
            const int row = tid & 127, h = tid >> 7;
            float s = 0.f;
#pragma unroll
            for (int t = 0; t < 16; t++)
                s += Psum[(size_t)(h * 16 + t) * N_NODES + m0 + row];
            red[tid] = s;
        }
        __syncthreads();
        if (tid < 128) {
            const float iv = 1.0f / (red[tid] + red[128 + tid]);
            invL[tid] = iv;
            if (nt == 0) st_sys(&inv[m0 + tid], iv);
        }
        __syncthreads();
        float qs = 0.f;
#pragma unroll
        for (int r = 0; r < 16; r++) {
            const int idx = r * 256 + tid;           // 0..4095
            const int row = idx >> 5;
            const float u = p[m0 + row] * adj[(size_t)m0 * EMBED + idx];
            Us[idx] = invL[row] * u;
            qs += u;                                 // d = tid&31 fixed
        }
        __syncthreads();
        if (nt == 0) {
            red[tid] = qs;
            __syncthreads();
            if (tid < 32) {
                float t = 0.f;
#pragma unroll
                for (int gg = 0; gg < 8; gg++) t += red[gg * 32 + tid];
                st_sys(&qpart[mc * EMBED + tid], t);
            }
            __syncthreads();
        }
        const int n  = nt * 128 + (tid & 127);
        const int dh = (tid >> 7) * 16;
        float4 a0 = {}, a1 = {}, a2 = {}, a3 = {};
        for (int mm = 0; mm < 128; mm++) {
            const float a = Ehat[(size_t)(m0 + mm) * N_NODES + n];
            const float4* u4 = (const float4*)(&Us[mm * 32 + dh]);
            const float4 u0 = u4[0], u1 = u4[1], u2 = u4[2], u3 = u4[3];
            a0.x += a * u0.x; a0.y += a * u0.y; a0.z += a * u0.z; a0.w += a * u0.w;
            a1.x += a * u1.x; a1.y += a * u1.y; a1.z += a * u1.z; a1.w += a * u1.w;
            a2.x += a * u2.x; a2.y += a * u2.y; a2.z += a * u2.z; a2.w += a * u2.w;
            a3.x += a * u3.x; a3.y += a * u3.y; a3.z += a * u3.z; a3.w += a * u3.w;
        }
        float* o = Vpa + (size_t)mc * (N_NODES * EMBED) + (size_t)n * EMBED + dh;
        st_sys4(o, a0); st_sys4(o + 4, a1); st_sys4(o + 8, a2); st_sys4(o + 12, a3);
    }
    grid_sync(bar, NB * 2);

    // ---------------- Phase 3: reduce Vpa -> V1, V1p ------------------------
    if (bid < 256) {
        const int idx = bid * 256 + tid;             // 0..65535 = n*32+d
        float s = 0.f;
#pragma unroll
        for (int c = 0; c < 16; c++) s += Vpa[(size_t)c * (N_NODES * EMBED) + idx];
        st_sys(&V1[idx], s);
        st_sys(&V1p[idx], inv[idx >> 5] * s);
    }
    grid_sync(bar, NB * 3);

    // ---------------- Phase 4: V2 partials ----------------------------------
    if (bid < 256) {
        float* Us = sm;              // 4096
        const int nt = bid >> 4;
        const int mc = bid & 15;
        const int m0 = mc * 128;
#pragma unroll
        for (int r = 0; r < 16; r++) {
            const int idx = r * 256 + tid;
            Us[idx] = V1p[(size_t)m0 * EMBED + idx];
        }
        __syncthreads();
        const int n  = nt * 128 + (tid & 127);
        const int dh = (tid >> 7) * 16;
        float4 a0 = {}, a1 = {}, a2 = {}, a3 = {};
        for (int mm = 0; mm < 128; mm++) {
            const float a = Ehat[(size_t)(m0 + mm) * N_NODES + n];
            const float4* u4 = (const float4*)(&Us[mm * 32 + dh]);
            const float4 u0 = u4[0], u1 = u4[1], u2 = u4[2], u3 = u4[3];
            a0.x += a * u0.x; a0.y += a * u0.y; a0.z += a * u0.z; a0.w += a * u0.w;
            a1.x += a * u1.x; a1.y += a * u1.y; a1.z += a * u1.z; a1.w += a * u1.w;
            a2.x += a * u2.x; a2.y += a * u2.y; a2.z += a * u2.z; a2.w += a * u2.w;
            a3.x += a * u3.x; a3.y += a * u3.y; a3.z += a * u3.z; a3.w += a * u3.w;
        }
        float* o = Vpb + (size_t)mc * (N_NODES * EMBED) + (size_t)n * EMBED + dh;
        st_sys4(o, a0); st_sys4(o + 4, a1); st_sys4(o + 8, a2); st_sys4(o + 12, a3);
    }
    grid_sync(bar, NB * 4);

    // ---------------- Phase 5: reduce Vpb -> V2 -----------------------------
    if (bid < 256) {
        const int idx = bid * 256 + tid;
        float s = 0.f;
#pragma unroll
        for (int c = 0; c < 16; c++) s += Vpb[(size_t)c * (N_NODES * EMBED) + idx];
        st_sys(&V2[idx], s);
    }
    grid_sync(bar, NB * 5);

    // ---------------- Phase 6: M partials -----------------------------------
    if (bid < 128) {
        float* xs = sm;              // [32][65] = 2080
        float* vs = sm + 2080;       // [3][1024]
        const int c0 = (bid >> 3) * 32;
        const int nc = bid & 7;      // 256-row n-chunk
        const int d  = tid >> 3;
        const int cg = (tid & 7) * 4;
        float acc[3][4] = {};
#pragma unroll
        for (int s = 0; s < 4; s++) {
            const int n0 = nc * 256 + s * 64;
            __syncthreads();
#pragma unroll
            for (int r = 0; r < 8; r++) {
                const int idx = r * 256 + tid;       // 0..2047
                xs[(idx >> 6) * 65 + (idx & 63)] = XT[(size_t)(c0 + (idx >> 6)) * N_NODES + n0 + (idx & 63)];
            }
#pragma unroll
            for (int h = 0; h < 2; h++) {
                __syncthreads();
#pragma unroll
                for (int r = 0; r < 4; r++) {
                    const int idx = r * 256 + tid;   // 0..1023
                    const int row = n0 + h * 32;
                    vs[idx]        = p[row + (idx >> 5)] * adj[(size_t)row * EMBED + idx];
                    vs[1024 + idx] = V1[(size_t)row * EMBED + idx];
                    vs[2048 + idx] = V2[(size_t)row * EMBED + idx];
                }
                __syncthreads();
#pragma unroll 4
                for (int nn = 0; nn < 32; nn++) {
                    const float v0 = vs[nn * 32 + d];
                    const float v1 = vs[1024 + nn * 32 + d];
                    const float v2 = vs[2048 + nn * 32 + d];
#pragma unroll
                    for (int cc = 0; cc < 4; cc++) {
                        const float xv = xs[(cg + cc) * 65 + h * 32 + nn];
                        acc[0][cc] += xv * v0;
                        acc[1][cc] += xv * v1;
                        acc[2][cc] += xv * v2;
                    }
                }
            }
        }
#pragma unroll
        for (int k = 0; k < 3; k++)
            st_sys4(Mp + ((size_t)(nc * 3 + k) * EMBED + d) * NCOL + c0 + cg,
                    make_float4(acc[k][0], acc[k][1], acc[k][2], acc[k][3]));
    }
    grid_sync(bar, NB * 6);

    // ---------------- Phase 7: split-d epilogue -----------------------------
    if (bid < 32) {
        float* wL = sm;              // 3072
        float* mL = sm + 3072;       // 1536
        float* qL = sm + 4608;       // 32
        const int d = bid;
#pragma unroll
        for (int r = 0; r < 12; r++) {
            const int idx = r * 256 + tid;           // 0..3071
            const int k = idx >> 10;
            wL[idx] = W[((size_t)(d * 3 + k) << 10) + (idx & 1023)];
        }
#pragma unroll
        for (int r = 0; r < 6; r++) {
            const int e = r * 256 + tid;             // 0..1535
            const int k = e >> 9;
            const int c = e & 511;
            float s = 0.f;
#pragma unroll
            for (int ch = 0; ch < 8; ch++)
                s += Mp[((size_t)(ch * 3 + k) * EMBED + d) * NCOL + c];
            mL[k * 512 + c] = s;
        }
        if (d == 0 && tid < 32) {
            float s = 0.f;
#pragma unroll
            for (int mc = 0; mc < 16; mc++) s += qpart[mc * EMBED + tid];
            qL[tid] = s;
        }
        __syncthreads();
#pragma unroll
        for (int r = 0; r < 2; r++) {
            const int pair = r * 256 + tid;          // 0..511 = b*32+o
            const int b = pair >> 5;
            const int o = pair & 31;
            float acc = 0.f;
#pragma unroll
            for (int i = 0; i < 32; i++) {
                const float m0 = mL[b * 32 + i];
                const float m1 = mL[512 + b * 32 + i];
                const float m2 = mL[1024 + b * 32 + i];
                const float w0 = wL[i * 32 + o];
                const float w1 = wL[1024 + i * 32 + o];
                const float w2 = wL[2048 + i * 32 + o];
                acc += m0 * (w0 - w2) + m1 * w1 + 2.f * m2 * w2;
            }
            if (d == 0) {
                float bias = pb[0];
#pragma unroll
                for (int dd = 0; dd < 32; dd++) bias += qL[dd] * bp[dd * OUTC + o];
                acc += bias;
            }
            atomicAdd(&out[pair], acc);
        }
    }
}

// ---------------------------------------------------------------------------
extern "C" void kernel_launch(void* const* d_in, const int* in_sizes, int n_in,
                              void* d_out, int out_size, void* d_ws, size_t ws_size,
                              hipStream_t stream)
{
    const float* x     = (const float*)d_in[0];
    const float* adj   = (const float*)d_in[1];
    const float* gamma = (const float*)d_in[2];
    const float* Wp    = (const float*)d_in[3];
    const float* bp    = (const float*)d_in[4];
    const float* pw    = (const float*)d_in[5];
    const float* pb    = (const float*)d_in[6];
    const float* drop  = (const float*)d_in[7];
    float* out = (float*)d_out;

    float* ws = (float*)d_ws;
    unsigned* bar = (unsigned*)ws;                            // 128 B
    float* Ehat  = ws + 32;                                   // 16 MB
    float* Vpa   = Ehat + (size_t)N_NODES * N_NODES;          // 4 MB (16 chunks)
    float* Vpb   = Vpa  + (size_t)16 * N_NODES * EMBED;       // 4 MB
    float* Mp    = Vpb  + (size_t)16 * N_NODES * EMBED;       // 1.5 MB (8 chunks)
    float* Psum  = Mp   + (size_t)8 * CHEB_K * EMBED * NCOL;  // 256 KB
    float* inv   = Psum + (size_t)32 * N_NODES;               // 8 KB
    float* V1    = inv  + N_NODES;                            // 256 KB
    float* V1p   = V1   + (size_t)N_NODES * EMBED;            // 256 KB
    float* V2    = V1p  + (size_t)N_NODES * EMBED;            // 256 KB
    float* qpart = V2   + (size_t)N_NODES * EMBED;            // 2 KB

    hipMemsetAsync(bar, 0, 128, stream);
    k_fused<<<NB, 256, 0, stream>>>(x, adj, gamma, Wp, bp, pw, pb, drop,
                                    Ehat, Vpa, Vpb, Mp, Psum, inv,
                                    V1, V1p, V2, qpart, bar, out);
}